// Round 1
// baseline (2111.728 us; speedup 1.0000x reference)
//
#include <hip/hip_runtime.h>

// ---------- types ----------
typedef short short8 __attribute__((ext_vector_type(8)));   // 8 bf16 in 4 VGPRs
typedef float f32x4 __attribute__((ext_vector_type(4)));    // MFMA accumulator

#define N_USERS 4096
#define T_STEPS 64
#define SKEP 768
#define HDIM 256
#define KROLE 64
#define GDIM 1024   // 4*HDIM

// ---------- helpers ----------
__device__ __forceinline__ unsigned short f2bfs(float f) {
  unsigned int u = __builtin_bit_cast(unsigned int, f);
  u += 0x7fffu + ((u >> 16) & 1u);          // round-to-nearest-even
  return (unsigned short)(u >> 16);
}
__device__ __forceinline__ float bf2f(unsigned short b) {
  unsigned int u = ((unsigned int)b) << 16;
  return __builtin_bit_cast(float, u);
}
__device__ __forceinline__ short8 pack8(float4 a, float4 b) {
  short8 o;
  o[0] = (short)f2bfs(a.x); o[1] = (short)f2bfs(a.y);
  o[2] = (short)f2bfs(a.z); o[3] = (short)f2bfs(a.w);
  o[4] = (short)f2bfs(b.x); o[5] = (short)f2bfs(b.y);
  o[6] = (short)f2bfs(b.z); o[7] = (short)f2bfs(b.w);
  return o;
}
__device__ __forceinline__ float sigm(float x) { return 1.0f / (1.0f + __expf(-x)); }
__device__ __forceinline__ float tanh_(float x) { return 1.0f - 2.0f / (1.0f + __expf(2.0f * x)); }

// ---------- prep: W_cat = [W_hh | W_ih] bf16, rows permuted gate-interleaved ----------
// out col c: gate gi = (c>>4)&3, unit u = ((c>>6)<<4)|(c&15)  -> orig row = gi*256+u
__global__ __launch_bounds__(256) void k_prep(
    const float* __restrict__ Wih, const float* __restrict__ Whh,
    const float* __restrict__ bih, const float* __restrict__ bhh,
    unsigned short* __restrict__ wcat, float* __restrict__ bias)
{
  int c = blockIdx.x;
  int gi = (c >> 4) & 3;
  int u = ((c >> 6) << 4) | (c & 15);
  int orig = gi * HDIM + u;
  for (int k = threadIdx.x; k < 1024; k += 256) {
    float w = (k < HDIM) ? Whh[(size_t)orig * HDIM + k]
                         : Wih[(size_t)orig * SKEP + (k - HDIM)];
    wcat[(size_t)c * 1024 + k] = f2bfs(w);
  }
  if (threadIdx.x == 0) bias[c] = bih[orig] + bhh[orig];
}

// ---------- fused LSTM step: gates GEMM (MFMA bf16) + cell update ----------
// A[n, 0:256]=h_in(bf16), A[n,256:1024]=hist[n,t,:](fp32->bf16); B=wcat (bt layout)
__global__ __launch_bounds__(512) void k_step(
    const float* __restrict__ hist,
    const unsigned short* __restrict__ hin,
    unsigned short* __restrict__ hout,
    float* __restrict__ cst,
    const unsigned short* __restrict__ wcat,
    const float* __restrict__ bias,
    const int* __restrict__ lengths,
    int t)
{
  __shared__ __align__(16) unsigned char smem[65536];
  unsigned char* const A0 = smem;
  unsigned char* const B0 = smem + 16384;
  unsigned char* const A1 = smem + 32768;
  unsigned char* const B1 = smem + 49152;

  const int tid = threadIdx.x;
  const int lane = tid & 63;
  const int wid = tid >> 6;      // 0..7
  const int wr = wid >> 1;       // 0..3  rows
  const int wc = wid & 1;        // 0..1  cols
  const int lr = lane & 15;
  const int lg = lane >> 4;

  // XCD-grouped swizzle: 8 N-tiles of one M-stripe -> same XCD (same d%8)
  const int d = blockIdx.x;
  const int Mt = ((d >> 6) << 3) | (d & 7);   // 0..31
  const int Nt = (d >> 3) & 7;                // 0..7
  const int n0 = Mt * 128;
  const int c0 = Nt * 128;

  f32x4 acc[2][4];
#pragma unroll
  for (int mi = 0; mi < 2; ++mi)
#pragma unroll
    for (int nj = 0; nj < 4; ++nj) acc[mi][nj] = f32x4{0.f, 0.f, 0.f, 0.f};

  // staging geometry: task q in [0,1024): LDS row r=q>>3 (128B rows), chunk pc=q&7,
  // logical chunk cl = pc ^ (r&7)  (XOR swizzle, involution both sides)
  const int rr = tid >> 3;                       // 0..63
  const int cl = (tid & 7) ^ (rr & 7);
  const size_t hinA0 = (size_t)(n0 + rr) * HDIM + (size_t)cl * 8;
  const size_t hinA1 = (size_t)(n0 + rr + 64) * HDIM + (size_t)cl * 8;
  const size_t histA0 = ((size_t)(n0 + rr) * T_STEPS + t) * SKEP + (size_t)cl * 8;
  const size_t histA1 = ((size_t)(n0 + rr + 64) * T_STEPS + t) * SKEP + (size_t)cl * 8;
  const size_t wB0 = (size_t)(c0 + rr) * 1024 + (size_t)cl * 8;
  const size_t wB1 = (size_t)(c0 + rr + 64) * 1024 + (size_t)cl * 8;
  const int dst0 = tid * 16, dst1 = tid * 16 + 8192;

  // prologue: stage kt=0 (h-part) into buf0
  {
    short8 a0 = *(const short8*)(hin + hinA0);
    short8 a1 = *(const short8*)(hin + hinA1);
    short8 b0 = *(const short8*)(wcat + wB0);
    short8 b1 = *(const short8*)(wcat + wB1);
    *(short8*)(A0 + dst0) = a0;
    *(short8*)(A0 + dst1) = a1;
    *(short8*)(B0 + dst0) = b0;
    *(short8*)(B0 + dst1) = b1;
  }
  __syncthreads();

  for (int kt = 0; kt < 16; ++kt) {
    unsigned char* curA = (kt & 1) ? A1 : A0;
    unsigned char* curB = (kt & 1) ? B1 : B0;
    unsigned char* nxtA = (kt & 1) ? A0 : A1;
    unsigned char* nxtB = (kt & 1) ? B0 : B1;
    const int kn = kt + 1;
    const bool have = (kn < 16);
    const bool hpart = (kn < 4);

    short8 sa0, sa1, sb0, sb1;
    float4 f00, f01, f10, f11;
    if (have) {                      // issue next-tile global loads BEFORE compute
      if (hpart) {
        sa0 = *(const short8*)(hin + hinA0 + (size_t)kn * 64);
        sa1 = *(const short8*)(hin + hinA1 + (size_t)kn * 64);
      } else {
        const float* p0 = hist + histA0 + (size_t)(kn - 4) * 64;
        const float* p1 = hist + histA1 + (size_t)(kn - 4) * 64;
        f00 = *(const float4*)p0; f01 = *(const float4*)(p0 + 4);
        f10 = *(const float4*)p1; f11 = *(const float4*)(p1 + 4);
      }
      sb0 = *(const short8*)(wcat + wB0 + (size_t)kn * 64);
      sb1 = *(const short8*)(wcat + wB1 + (size_t)kn * 64);
    }

    // compute current K-tile (2 k-subtiles of 32)
#pragma unroll
    for (int ks = 0; ks < 2; ++ks) {
      short8 av[2], bv[4];
#pragma unroll
      for (int mi = 0; mi < 2; ++mi) {
        int r = wr * 32 + mi * 16 + lr;
        int c = ks * 4 + lg;
        int ph = c ^ (r & 7);
        av[mi] = *(const short8*)(curA + r * 128 + ph * 16);
      }
#pragma unroll
      for (int nj = 0; nj < 4; ++nj) {
        int r = wc * 64 + nj * 16 + lr;
        int c = ks * 4 + lg;
        int ph = c ^ (r & 7);
        bv[nj] = *(const short8*)(curB + r * 128 + ph * 16);
      }
#pragma unroll
      for (int mi = 0; mi < 2; ++mi)
#pragma unroll
        for (int nj = 0; nj < 4; ++nj)
          acc[mi][nj] = __builtin_amdgcn_mfma_f32_16x16x32_bf16(av[mi], bv[nj], acc[mi][nj], 0, 0, 0);
    }

    if (have) {                      // convert + ds_write AFTER compute (latency hidden)
      if (!hpart) { sa0 = pack8(f00, f01); sa1 = pack8(f10, f11); }
      *(short8*)(nxtA + dst0) = sa0;
      *(short8*)(nxtA + dst1) = sa1;
      *(short8*)(nxtB + dst0) = sb0;
      *(short8*)(nxtB + dst1) = sb1;
    }
    __syncthreads();
  }

  // ---------- epilogue: LSTM cell, fully in-register ----------
  // lane's 4 nj-fragments are gates i,f,g,o of unit: col = c0 + wc*64 + nj*16 + lr
  const int unitg = Nt * 32 + wc * 16 + lr;    // global hidden unit
  float bs[4];
#pragma unroll
  for (int gi = 0; gi < 4; ++gi) bs[gi] = bias[c0 + wc * 64 + gi * 16 + lr];

#pragma unroll
  for (int mi = 0; mi < 2; ++mi) {
#pragma unroll
    for (int q = 0; q < 4; ++q) {
      int row = wr * 32 + mi * 16 + lg * 4 + q;
      int n = n0 + row;
      size_t cx = (size_t)n * HDIM + unitg;
      float gi_ = sigm(acc[mi][0][q] + bs[0]);
      float gf_ = sigm(acc[mi][1][q] + bs[1]);
      float gg_ = tanh_(acc[mi][2][q] + bs[2]);
      float go_ = sigm(acc[mi][3][q] + bs[3]);
      float co = cst[cx];
      float cn = gf_ * co + gi_ * gg_;
      float hn = go_ * tanh_(cn);
      if (t < lengths[n]) {
        cst[cx] = cn;
        hout[cx] = f2bfs(hn);
      } else {
        hout[cx] = hin[cx];          // carry h through ping-pong
      }
    }
  }
}

// ---------- Phase C1: s[n] = dot(cc[cid[n]], uv[n]) / sqrt(H) ----------
__global__ __launch_bounds__(256) void k_scores(
    const float* __restrict__ uv, const float* __restrict__ cc,
    const int* __restrict__ cid, float* __restrict__ s)
{
  int n = blockIdx.x * 4 + (threadIdx.x >> 6);
  int lane = threadIdx.x & 63;
  float4 a = *(const float4*)(uv + (size_t)n * HDIM + lane * 4);
  float4 b = *(const float4*)(cc + (size_t)cid[n] * HDIM + lane * 4);
  float dd = a.x * b.x + a.y * b.y + a.z * b.z + a.w * b.w;
  for (int off = 32; off; off >>= 1) dd += __shfl_down(dd, off);
  if (lane == 0) s[n] = dd * 0.0625f;   // 1/sqrt(256)
}

// ---------- Phase C2: segment softmax + role_senti[k][:] ----------
__global__ __launch_bounds__(256) void k_role(
    const float* __restrict__ s, const int* __restrict__ cid,
    const unsigned short* __restrict__ hn, float* __restrict__ rs)
{
  __shared__ float sv[N_USERS];
  __shared__ int cv[N_USERS];
  __shared__ float red[256];
  const int k = blockIdx.x, tid = threadIdx.x;
  for (int i = tid; i < N_USERS; i += 256) { sv[i] = s[i]; cv[i] = cid[i]; }
  __syncthreads();
  float m = -3.4e38f;
  for (int i = tid; i < N_USERS; i += 256) if (cv[i] == k) m = fmaxf(m, sv[i]);
  red[tid] = m; __syncthreads();
  for (int st = 128; st; st >>= 1) { if (tid < st) red[tid] = fmaxf(red[tid], red[tid + st]); __syncthreads(); }
  const float smax = red[0];
  __syncthreads();
  float sum = 0.f;
  for (int i = tid; i < N_USERS; i += 256)
    if (cv[i] == k) { float e = __expf(sv[i] - smax); sv[i] = e; sum += e; }
  red[tid] = sum; __syncthreads();
  for (int st = 128; st; st >>= 1) { if (tid < st) red[tid] += red[tid + st]; __syncthreads(); }
  const float den = red[0];
  __syncthreads();
  float a = 0.f;
  for (int i = 0; i < N_USERS; ++i)
    if (cv[i] == k) a += sv[i] * bf2f(hn[(size_t)i * HDIM + tid]);
  rs[(size_t)k * HDIM + tid] = a / den;
}

// ---------- Phase D1: per-head MHA over roles ----------
__global__ __launch_bounds__(256) void k_mha(
    const float* __restrict__ rs,
    const float* __restrict__ Wq, const float* __restrict__ bq,
    const float* __restrict__ Wk, const float* __restrict__ bk,
    const float* __restrict__ Wv, const float* __restrict__ bv,
    float* __restrict__ attout)
{
  __shared__ float q[64][32], kk[64][32], v[64][32];
  __shared__ float att[64][64];
  const int h = blockIdx.x, tid = threadIdx.x;
  for (int idx = tid; idx < 2048; idx += 256) {
    int r = idx >> 5, dd2 = idx & 31;
    int wrow = h * 32 + dd2;
    float aq = bq[wrow], ak = bk[wrow], av = bv[wrow];
    const float* x = rs + (size_t)r * HDIM;
    const float* wq = Wq + (size_t)wrow * HDIM;
    const float* wk = Wk + (size_t)wrow * HDIM;
    const float* wv = Wv + (size_t)wrow * HDIM;
    for (int j = 0; j < HDIM; ++j) {
      float xv = x[j];
      aq += xv * wq[j]; ak += xv * wk[j]; av += xv * wv[j];
    }
    q[r][dd2] = aq; kk[r][dd2] = ak; v[r][dd2] = av;
  }
  __syncthreads();
  for (int idx = tid; idx < 4096; idx += 256) {
    int qr = idx >> 6, kr = idx & 63;
    float sc = 0.f;
    for (int dd2 = 0; dd2 < 32; ++dd2) sc += q[qr][dd2] * kk[kr][dd2];
    att[qr][kr] = sc * 0.17677669529663687f;   // 1/sqrt(32)
  }
  __syncthreads();
  if (tid < 64) {
    float m = -3.4e38f;
    for (int j = 0; j < 64; ++j) m = fmaxf(m, att[tid][j]);
    float sum = 0.f;
    for (int j = 0; j < 64; ++j) { float e = __expf(att[tid][j] - m); att[tid][j] = e; sum += e; }
    float inv = 1.f / sum;
    for (int j = 0; j < 64; ++j) att[tid][j] *= inv;
  }
  __syncthreads();
  for (int idx = tid; idx < 2048; idx += 256) {
    int r = idx >> 5, dd2 = idx & 31;
    float o = 0.f;
    for (int kr = 0; kr < 64; ++kr) o += att[r][kr] * v[kr][dd2];
    attout[(size_t)r * HDIM + h * 32 + dd2] = o;
  }
}

// ---------- Phase D2: mean over roles + Wo projection ----------
__global__ __launch_bounds__(256) void k_out(
    const float* __restrict__ attout, const float* __restrict__ Wo,
    const float* __restrict__ bo, float* __restrict__ out)
{
  __shared__ float m_s[256];
  const int tid = threadIdx.x;
  float mm = 0.f;
  for (int r = 0; r < 64; ++r) mm += attout[(size_t)r * HDIM + tid];
  m_s[tid] = mm * (1.0f / 64.0f);
  __syncthreads();
  float a = bo[tid];
  for (int j = 0; j < HDIM; ++j) a += m_s[j] * Wo[(size_t)tid * HDIM + j];
  out[tid] = a;
}

extern "C" void kernel_launch(void* const* d_in, const int* in_sizes, int n_in,
                              void* d_out, int out_size, void* d_ws, size_t ws_size,
                              hipStream_t stream) {
  const float* hist = (const float*)d_in[0];
  const float* uv   = (const float*)d_in[1];
  const float* cc   = (const float*)d_in[2];
  const float* Wih  = (const float*)d_in[3];
  const float* Whh  = (const float*)d_in[4];
  const float* bih  = (const float*)d_in[5];
  const float* bhh  = (const float*)d_in[6];
  const float* Wq   = (const float*)d_in[7];
  const float* bq   = (const float*)d_in[8];
  const float* Wk   = (const float*)d_in[9];
  const float* bk   = (const float*)d_in[10];
  const float* Wv   = (const float*)d_in[11];
  const float* bv   = (const float*)d_in[12];
  const float* Wo   = (const float*)d_in[13];
  const float* bo   = (const float*)d_in[14];
  const int* lengths = (const int*)d_in[15];
  const int* cid     = (const int*)d_in[16];
  float* out = (float*)d_out;

  unsigned char* ws = (unsigned char*)d_ws;
  unsigned short* hbuf0 = (unsigned short*)(ws);                    // 2 MB
  unsigned short* hbuf1 = (unsigned short*)(ws + (1u << 21));       // 2 MB
  float* cst   = (float*)(ws + (2u << 21));                         // 4 MB
  unsigned short* wcat = (unsigned short*)(ws + (4u << 21));        // 2 MB
  float* bias  = (float*)(ws + (5u << 21));                         // 4 KB
  float* sbuf  = (float*)(ws + (5u << 21) + 8192);                  // 16 KB
  float* rs    = (float*)(ws + (5u << 21) + 32768);                 // 64 KB
  float* attout= (float*)(ws + (5u << 21) + 32768 + 65536);         // 64 KB
  if (ws_size < (size_t)(5u << 21) + 262144) return;                // need ~10.7 MB

  hipMemsetAsync(hbuf0, 0, (size_t)N_USERS * HDIM * 2, stream);
  hipMemsetAsync(cst,   0, (size_t)N_USERS * HDIM * 4, stream);

  k_prep<<<1024, 256, 0, stream>>>(Wih, Whh, bih, bhh, wcat, bias);

  for (int t = 0; t < T_STEPS; ++t) {
    const unsigned short* hin = (t & 1) ? hbuf1 : hbuf0;
    unsigned short* hout      = (t & 1) ? hbuf0 : hbuf1;
    k_step<<<256, 512, 0, stream>>>(hist, hin, hout, cst, wcat, bias, lengths, t);
  }
  // final h is in hbuf0 (t=63 writes hbuf0)

  k_scores<<<1024, 256, 0, stream>>>(uv, cc, cid, sbuf);
  k_role<<<64, 256, 0, stream>>>(sbuf, cid, hbuf0, rs);
  k_mha<<<8, 256, 0, stream>>>(rs, Wq, bq, Wk, bk, Wv, bv, attout);
  k_out<<<1, 256, 0, stream>>>(attout, Wo, bo, out);
}

// Round 2
// 1835.866 us; speedup vs baseline: 1.1503x; 1.1503x over previous
//
#include <hip/hip_runtime.h>

// ---------- types ----------
typedef short short8 __attribute__((ext_vector_type(8)));   // 8 bf16 in 4 VGPRs
typedef float f32x4 __attribute__((ext_vector_type(4)));    // MFMA accumulator

#define N_USERS 4096
#define T_STEPS 64
#define SKEP 768
#define HDIM 256
#define KROLE 64

// ---------- helpers ----------
__device__ __forceinline__ unsigned short f2bfs(float f) {
  unsigned int u = __builtin_bit_cast(unsigned int, f);
  u += 0x7fffu + ((u >> 16) & 1u);          // round-to-nearest-even
  return (unsigned short)(u >> 16);
}
__device__ __forceinline__ float bf2f(unsigned short b) {
  unsigned int u = ((unsigned int)b) << 16;
  return __builtin_bit_cast(float, u);
}
__device__ __forceinline__ short8 pack8(float4 a, float4 b) {
  short8 o;
  o[0] = (short)f2bfs(a.x); o[1] = (short)f2bfs(a.y);
  o[2] = (short)f2bfs(a.z); o[3] = (short)f2bfs(a.w);
  o[4] = (short)f2bfs(b.x); o[5] = (short)f2bfs(b.y);
  o[6] = (short)f2bfs(b.z); o[7] = (short)f2bfs(b.w);
  return o;
}
__device__ __forceinline__ float sigm(float x) { return 1.0f / (1.0f + __expf(-x)); }
__device__ __forceinline__ float tanh_(float x) { return 1.0f - 2.0f / (1.0f + __expf(2.0f * x)); }

// ---------- prep: W_cat = [W_hh | W_ih] bf16, rows permuted gate-interleaved ----------
// gate-col c: gate gi=(c>>4)&3, unit u=((c>>6)<<4)|(c&15) -> orig row gi*256+u
// wcat[c][0:256]=W_hh[orig], wcat[c][256:1024]=W_ih[orig]
__global__ __launch_bounds__(256) void k_prep(
    const float* __restrict__ Wih, const float* __restrict__ Whh,
    const float* __restrict__ bih, const float* __restrict__ bhh,
    unsigned short* __restrict__ wcat, float* __restrict__ bias)
{
  int c = blockIdx.x;
  int gi = (c >> 4) & 3;
  int u = ((c >> 6) << 4) | (c & 15);
  int orig = gi * HDIM + u;
  for (int k = threadIdx.x; k < 1024; k += 256) {
    float w = (k < HDIM) ? Whh[(size_t)orig * HDIM + k]
                         : Wih[(size_t)orig * SKEP + (k - HDIM)];
    wcat[(size_t)c * 1024 + k] = f2bfs(w);
  }
  if (threadIdx.x == 0) bias[c] = bih[orig] + bhh[orig];
}

// ---------- k_bigx: X[r][gatecol] = hist_row[r] @ W_ih^T (bf16 out) ----------
// r = n*T + t (hist is [N][T][768] contiguous). M=262144, K=768, N=1024.
// 128x128 tile, BK=64. Inverse-XCD swizzle: the 8 Nt blocks of one Mt are
// consecutive on ONE XCD -> A-tile L2-reuse (L3 is the backstop).
__global__ __launch_bounds__(512) void k_bigx(
    const float* __restrict__ hist,
    const unsigned short* __restrict__ wcat,
    unsigned short* __restrict__ X)
{
  __shared__ __align__(16) unsigned char smem[65536];
  unsigned char* const A0 = smem;
  unsigned char* const B0 = smem + 16384;
  unsigned char* const A1 = smem + 32768;
  unsigned char* const B1 = smem + 49152;

  const int tid = threadIdx.x;
  const int lane = tid & 63;
  const int wid = tid >> 6;
  const int wr = wid >> 1;       // 0..3
  const int wc = wid & 1;        // 0..1
  const int lr = lane & 15;
  const int lg = lane >> 4;

  const int d = blockIdx.x;
  const int xcd = d & 7;
  const int s = d >> 3;
  const int Nt = s & 7;                       // 0..7
  const int Mt = (s >> 3) * 8 + xcd;          // 0..2047, Mt%8==xcd
  const size_t r0 = (size_t)Mt * 128;
  const int c0 = Nt * 128;

  f32x4 acc[2][4];
#pragma unroll
  for (int mi = 0; mi < 2; ++mi)
#pragma unroll
    for (int nj = 0; nj < 4; ++nj) acc[mi][nj] = f32x4{0.f, 0.f, 0.f, 0.f};

  const int rr = tid >> 3;                    // 0..63
  const int cl = (tid & 7) ^ (rr & 7);        // XOR swizzle chunk
  const size_t hA0 = (r0 + rr) * (size_t)SKEP + (size_t)cl * 8;
  const size_t hA1 = (r0 + rr + 64) * (size_t)SKEP + (size_t)cl * 8;
  const size_t wB0 = (size_t)(c0 + rr) * 1024 + 256 + (size_t)cl * 8;
  const size_t wB1 = (size_t)(c0 + rr + 64) * 1024 + 256 + (size_t)cl * 8;
  const int dst0 = tid * 16, dst1 = tid * 16 + 8192;

  // prologue: stage kt=0
  {
    const float* p0 = hist + hA0;
    const float* p1 = hist + hA1;
    float4 f00 = *(const float4*)p0, f01 = *(const float4*)(p0 + 4);
    float4 f10 = *(const float4*)p1, f11 = *(const float4*)(p1 + 4);
    short8 b0 = *(const short8*)(wcat + wB0);
    short8 b1 = *(const short8*)(wcat + wB1);
    *(short8*)(A0 + dst0) = pack8(f00, f01);
    *(short8*)(A0 + dst1) = pack8(f10, f11);
    *(short8*)(B0 + dst0) = b0;
    *(short8*)(B0 + dst1) = b1;
  }
  __syncthreads();

  for (int kt = 0; kt < 12; ++kt) {
    unsigned char* curA = (kt & 1) ? A1 : A0;
    unsigned char* curB = (kt & 1) ? B1 : B0;
    unsigned char* nxtA = (kt & 1) ? A0 : A1;
    unsigned char* nxtB = (kt & 1) ? B0 : B1;
    const int kn = kt + 1;
    const bool have = (kn < 12);

    float4 f00, f01, f10, f11;
    short8 sb0, sb1;
    if (have) {
      const float* p0 = hist + hA0 + (size_t)kn * 64;
      const float* p1 = hist + hA1 + (size_t)kn * 64;
      f00 = *(const float4*)p0; f01 = *(const float4*)(p0 + 4);
      f10 = *(const float4*)p1; f11 = *(const float4*)(p1 + 4);
      sb0 = *(const short8*)(wcat + wB0 + (size_t)kn * 64);
      sb1 = *(const short8*)(wcat + wB1 + (size_t)kn * 64);
    }

#pragma unroll
    for (int ks = 0; ks < 2; ++ks) {
      short8 av[2], bv[4];
#pragma unroll
      for (int mi = 0; mi < 2; ++mi) {
        int r = wr * 32 + mi * 16 + lr;
        int c = ks * 4 + lg;
        int ph = c ^ (r & 7);
        av[mi] = *(const short8*)(curA + r * 128 + ph * 16);
      }
#pragma unroll
      for (int nj = 0; nj < 4; ++nj) {
        int r = wc * 64 + nj * 16 + lr;
        int c = ks * 4 + lg;
        int ph = c ^ (r & 7);
        bv[nj] = *(const short8*)(curB + r * 128 + ph * 16);
      }
#pragma unroll
      for (int mi = 0; mi < 2; ++mi)
#pragma unroll
        for (int nj = 0; nj < 4; ++nj)
          acc[mi][nj] = __builtin_amdgcn_mfma_f32_16x16x32_bf16(av[mi], bv[nj], acc[mi][nj], 0, 0, 0);
    }

    if (have) {
      *(short8*)(nxtA + dst0) = pack8(f00, f01);
      *(short8*)(nxtA + dst1) = pack8(f10, f11);
      *(short8*)(nxtB + dst0) = sb0;
      *(short8*)(nxtB + dst1) = sb1;
    }
    __syncthreads();
  }

  // epilogue: X bf16 out
#pragma unroll
  for (int mi = 0; mi < 2; ++mi) {
#pragma unroll
    for (int q = 0; q < 4; ++q) {
      int row = wr * 32 + mi * 16 + lg * 4 + q;
      size_t ob = (r0 + row) * 1024 + c0 + wc * 64 + lr;
#pragma unroll
      for (int nj = 0; nj < 4; ++nj)
        X[ob + nj * 16] = f2bfs(acc[mi][nj][q]);
    }
  }
}

// ---------- k_step2: gates = h @ W_hh^T + X_t + bias; cell update ----------
// K=256 (4 chunks of 64). X tile prefetched to registers before the K-loop.
__global__ __launch_bounds__(512) void k_step2(
    const unsigned short* __restrict__ X,
    const unsigned short* __restrict__ hin,
    unsigned short* __restrict__ hout,
    float* __restrict__ cst,
    const unsigned short* __restrict__ wcat,
    const float* __restrict__ bias,
    const int* __restrict__ lengths,
    int t)
{
  __shared__ __align__(16) unsigned char smem[65536];
  unsigned char* const A0 = smem;
  unsigned char* const B0 = smem + 16384;
  unsigned char* const A1 = smem + 32768;
  unsigned char* const B1 = smem + 49152;

  const int tid = threadIdx.x;
  const int lane = tid & 63;
  const int wid = tid >> 6;
  const int wr = wid >> 1;
  const int wc = wid & 1;
  const int lr = lane & 15;
  const int lg = lane >> 4;

  const int d = blockIdx.x;
  const int Mt = ((d >> 6) << 3) | (d & 7);   // 0..31
  const int Nt = (d >> 3) & 7;                // 0..7
  const int n0 = Mt * 128;
  const int c0 = Nt * 128;

  f32x4 acc[2][4];
#pragma unroll
  for (int mi = 0; mi < 2; ++mi)
#pragma unroll
    for (int nj = 0; nj < 4; ++nj) acc[mi][nj] = f32x4{0.f, 0.f, 0.f, 0.f};

  const int rr = tid >> 3;
  const int cl = (tid & 7) ^ (rr & 7);
  const size_t hinA0 = (size_t)(n0 + rr) * HDIM + (size_t)cl * 8;
  const size_t hinA1 = (size_t)(n0 + rr + 64) * HDIM + (size_t)cl * 8;
  const size_t wB0 = (size_t)(c0 + rr) * 1024 + (size_t)cl * 8;
  const size_t wB1 = (size_t)(c0 + rr + 64) * 1024 + (size_t)cl * 8;
  const int dst0 = tid * 16, dst1 = tid * 16 + 8192;

  // prologue: stage kt=0
  {
    short8 a0 = *(const short8*)(hin + hinA0);
    short8 a1 = *(const short8*)(hin + hinA1);
    short8 b0 = *(const short8*)(wcat + wB0);
    short8 b1 = *(const short8*)(wcat + wB1);
    *(short8*)(A0 + dst0) = a0;
    *(short8*)(A0 + dst1) = a1;
    *(short8*)(B0 + dst0) = b0;
    *(short8*)(B0 + dst1) = b1;
  }

  // X-tile prefetch into registers (issued before K-loop; used at epilogue)
  unsigned short xg[2][4][4];
#pragma unroll
  for (int mi = 0; mi < 2; ++mi) {
#pragma unroll
    for (int q = 0; q < 4; ++q) {
      int row = wr * 32 + mi * 16 + lg * 4 + q;
      const unsigned short* xp =
          X + ((size_t)(n0 + row) * T_STEPS + t) * 1024 + c0 + wc * 64 + lr;
#pragma unroll
      for (int nj = 0; nj < 4; ++nj) xg[mi][nj][q] = xp[nj * 16];
    }
  }
  __syncthreads();

  for (int kt = 0; kt < 4; ++kt) {
    unsigned char* curA = (kt & 1) ? A1 : A0;
    unsigned char* curB = (kt & 1) ? B1 : B0;
    unsigned char* nxtA = (kt & 1) ? A0 : A1;
    unsigned char* nxtB = (kt & 1) ? B0 : B1;
    const int kn = kt + 1;
    const bool have = (kn < 4);

    short8 sa0, sa1, sb0, sb1;
    if (have) {
      sa0 = *(const short8*)(hin + hinA0 + (size_t)kn * 64);
      sa1 = *(const short8*)(hin + hinA1 + (size_t)kn * 64);
      sb0 = *(const short8*)(wcat + wB0 + (size_t)kn * 64);
      sb1 = *(const short8*)(wcat + wB1 + (size_t)kn * 64);
    }

#pragma unroll
    for (int ks = 0; ks < 2; ++ks) {
      short8 av[2], bv[4];
#pragma unroll
      for (int mi = 0; mi < 2; ++mi) {
        int r = wr * 32 + mi * 16 + lr;
        int c = ks * 4 + lg;
        int ph = c ^ (r & 7);
        av[mi] = *(const short8*)(curA + r * 128 + ph * 16);
      }
#pragma unroll
      for (int nj = 0; nj < 4; ++nj) {
        int r = wc * 64 + nj * 16 + lr;
        int c = ks * 4 + lg;
        int ph = c ^ (r & 7);
        bv[nj] = *(const short8*)(curB + r * 128 + ph * 16);
      }
#pragma unroll
      for (int mi = 0; mi < 2; ++mi)
#pragma unroll
        for (int nj = 0; nj < 4; ++nj)
          acc[mi][nj] = __builtin_amdgcn_mfma_f32_16x16x32_bf16(av[mi], bv[nj], acc[mi][nj], 0, 0, 0);
    }

    if (have) {
      *(short8*)(nxtA + dst0) = sa0;
      *(short8*)(nxtA + dst1) = sa1;
      *(short8*)(nxtB + dst0) = sb0;
      *(short8*)(nxtB + dst1) = sb1;
    }
    __syncthreads();
  }

  // epilogue: LSTM cell in-register (nj = gate i,f,g,o)
  const int unitg = Nt * 32 + wc * 16 + lr;
  float bs[4];
#pragma unroll
  for (int gi = 0; gi < 4; ++gi) bs[gi] = bias[c0 + wc * 64 + gi * 16 + lr];

#pragma unroll
  for (int mi = 0; mi < 2; ++mi) {
#pragma unroll
    for (int q = 0; q < 4; ++q) {
      int row = wr * 32 + mi * 16 + lg * 4 + q;
      int n = n0 + row;
      size_t cx = (size_t)n * HDIM + unitg;
      if (t < lengths[n]) {
        float gi_ = sigm(acc[mi][0][q] + bf2f(xg[mi][0][q]) + bs[0]);
        float gf_ = sigm(acc[mi][1][q] + bf2f(xg[mi][1][q]) + bs[1]);
        float gg_ = tanh_(acc[mi][2][q] + bf2f(xg[mi][2][q]) + bs[2]);
        float go_ = sigm(acc[mi][3][q] + bf2f(xg[mi][3][q]) + bs[3]);
        float co = cst[cx];
        float cn = gf_ * co + gi_ * gg_;
        cst[cx] = cn;
        hout[cx] = f2bfs(go_ * tanh_(cn));
      } else {
        hout[cx] = hin[cx];          // carry h through ping-pong; c untouched
      }
    }
  }
}

// ---------- Phase C1: s[n] = dot(cc[cid[n]], uv[n]) / sqrt(H) ----------
__global__ __launch_bounds__(256) void k_scores(
    const float* __restrict__ uv, const float* __restrict__ cc,
    const int* __restrict__ cid, float* __restrict__ s)
{
  int n = blockIdx.x * 4 + (threadIdx.x >> 6);
  int lane = threadIdx.x & 63;
  float4 a = *(const float4*)(uv + (size_t)n * HDIM + lane * 4);
  float4 b = *(const float4*)(cc + (size_t)cid[n] * HDIM + lane * 4);
  float dd = a.x * b.x + a.y * b.y + a.z * b.z + a.w * b.w;
  for (int off = 32; off; off >>= 1) dd += __shfl_down(dd, off);
  if (lane == 0) s[n] = dd * 0.0625f;   // 1/sqrt(256)
}

// ---------- Phase C2: segment softmax + role_senti ----------
__global__ __launch_bounds__(256) void k_role(
    const float* __restrict__ s, const int* __restrict__ cid,
    const unsigned short* __restrict__ hn, float* __restrict__ rs)
{
  __shared__ float sv[N_USERS];
  __shared__ int cv[N_USERS];
  __shared__ float red[256];
  const int k = blockIdx.x, tid = threadIdx.x;
  for (int i = tid; i < N_USERS; i += 256) { sv[i] = s[i]; cv[i] = cid[i]; }
  __syncthreads();
  float m = -3.4e38f;
  for (int i = tid; i < N_USERS; i += 256) if (cv[i] == k) m = fmaxf(m, sv[i]);
  red[tid] = m; __syncthreads();
  for (int st = 128; st; st >>= 1) { if (tid < st) red[tid] = fmaxf(red[tid], red[tid + st]); __syncthreads(); }
  const float smax = red[0];
  __syncthreads();
  float sum = 0.f;
  for (int i = tid; i < N_USERS; i += 256)
    if (cv[i] == k) { float e = __expf(sv[i] - smax); sv[i] = e; sum += e; }
  red[tid] = sum; __syncthreads();
  for (int st = 128; st; st >>= 1) { if (tid < st) red[tid] += red[tid + st]; __syncthreads(); }
  const float den = red[0];
  __syncthreads();
  float a = 0.f;
  for (int i = 0; i < N_USERS; ++i)
    if (cv[i] == k) a += sv[i] * bf2f(hn[(size_t)i * HDIM + tid]);
  rs[(size_t)k * HDIM + tid] = a / den;
}

// ---------- Phase D1: per-head MHA over roles ----------
__global__ __launch_bounds__(256) void k_mha(
    const float* __restrict__ rs,
    const float* __restrict__ Wq, const float* __restrict__ bq,
    const float* __restrict__ Wk, const float* __restrict__ bk,
    const float* __restrict__ Wv, const float* __restrict__ bv,
    float* __restrict__ attout)
{
  __shared__ float q[64][32], kk[64][32], v[64][32];
  __shared__ float att[64][64];
  const int h = blockIdx.x, tid = threadIdx.x;
  for (int idx = tid; idx < 2048; idx += 256) {
    int r = idx >> 5, dd2 = idx & 31;
    int wrow = h * 32 + dd2;
    float aq = bq[wrow], ak = bk[wrow], av = bv[wrow];
    const float* x = rs + (size_t)r * HDIM;
    const float* wq = Wq + (size_t)wrow * HDIM;
    const float* wk = Wk + (size_t)wrow * HDIM;
    const float* wv = Wv + (size_t)wrow * HDIM;
    for (int j = 0; j < HDIM; ++j) {
      float xv = x[j];
      aq += xv * wq[j]; ak += xv * wk[j]; av += xv * wv[j];
    }
    q[r][dd2] = aq; kk[r][dd2] = ak; v[r][dd2] = av;
  }
  __syncthreads();
  for (int idx = tid; idx < 4096; idx += 256) {
    int qr = idx >> 6, kr = idx & 63;
    float sc = 0.f;
    for (int dd2 = 0; dd2 < 32; ++dd2) sc += q[qr][dd2] * kk[kr][dd2];
    att[qr][kr] = sc * 0.17677669529663687f;   // 1/sqrt(32)
  }
  __syncthreads();
  if (tid < 64) {
    float m = -3.4e38f;
    for (int j = 0; j < 64; ++j) m = fmaxf(m, att[tid][j]);
    float sum = 0.f;
    for (int j = 0; j < 64; ++j) { float e = __expf(att[tid][j] - m); att[tid][j] = e; sum += e; }
    float inv = 1.f / sum;
    for (int j = 0; j < 64; ++j) att[tid][j] *= inv;
  }
  __syncthreads();
  for (int idx = tid; idx < 2048; idx += 256) {
    int r = idx >> 5, dd2 = idx & 31;
    float o = 0.f;
    for (int kr = 0; kr < 64; ++kr) o += att[r][kr] * v[kr][dd2];
    attout[(size_t)r * HDIM + h * 32 + dd2] = o;
  }
}

// ---------- Phase D2: mean over roles + Wo projection ----------
__global__ __launch_bounds__(256) void k_out(
    const float* __restrict__ attout, const float* __restrict__ Wo,
    const float* __restrict__ bo, float* __restrict__ out)
{
  __shared__ float m_s[256];
  const int tid = threadIdx.x;
  float mm = 0.f;
  for (int r = 0; r < 64; ++r) mm += attout[(size_t)r * HDIM + tid];
  m_s[tid] = mm * (1.0f / 64.0f);
  __syncthreads();
  float a = bo[tid];
  for (int j = 0; j < HDIM; ++j) a += m_s[j] * Wo[(size_t)tid * HDIM + j];
  out[tid] = a;
}

extern "C" void kernel_launch(void* const* d_in, const int* in_sizes, int n_in,
                              void* d_out, int out_size, void* d_ws, size_t ws_size,
                              hipStream_t stream) {
  const float* hist = (const float*)d_in[0];
  const float* uv   = (const float*)d_in[1];
  const float* cc   = (const float*)d_in[2];
  const float* Wih  = (const float*)d_in[3];
  const float* Whh  = (const float*)d_in[4];
  const float* bih  = (const float*)d_in[5];
  const float* bhh  = (const float*)d_in[6];
  const float* Wq   = (const float*)d_in[7];
  const float* bq   = (const float*)d_in[8];
  const float* Wk   = (const float*)d_in[9];
  const float* bk   = (const float*)d_in[10];
  const float* Wv   = (const float*)d_in[11];
  const float* bv   = (const float*)d_in[12];
  const float* Wo   = (const float*)d_in[13];
  const float* bo   = (const float*)d_in[14];
  const int* lengths = (const int*)d_in[15];
  const int* cid     = (const int*)d_in[16];
  float* out = (float*)d_out;

  unsigned char* ws = (unsigned char*)d_ws;
  unsigned short* hbuf0 = (unsigned short*)(ws);                    // 2 MB
  unsigned short* hbuf1 = (unsigned short*)(ws + (1u << 21));       // 2 MB
  float* cst   = (float*)(ws + (2u << 21));                         // 4 MB
  unsigned short* wcat = (unsigned short*)(ws + (4u << 21));        // 2 MB
  float* bias  = (float*)(ws + (5u << 21));                         // 4 KB
  float* sbuf  = (float*)(ws + (5u << 21) + 8192);                  // 16 KB
  float* rs    = (float*)(ws + (5u << 21) + 32768);                 // 64 KB
  float* attout= (float*)(ws + (5u << 21) + 32768 + 65536);         // 64 KB
  unsigned short* Xbuf = (unsigned short*)(ws + (8u << 21));        // 512 MB
  const size_t need = (size_t)(8u << 21) + (size_t)N_USERS * T_STEPS * 1024 * 2;
  if (ws_size < need) return;

  hipMemsetAsync(hbuf0, 0, (size_t)N_USERS * HDIM * 2, stream);
  hipMemsetAsync(cst,   0, (size_t)N_USERS * HDIM * 4, stream);

  k_prep<<<1024, 256, 0, stream>>>(Wih, Whh, bih, bhh, wcat, bias);
  k_bigx<<<16384, 512, 0, stream>>>(hist, wcat, Xbuf);

  for (int t = 0; t < T_STEPS; ++t) {
    const unsigned short* hin = (t & 1) ? hbuf1 : hbuf0;
    unsigned short* hout      = (t & 1) ? hbuf0 : hbuf1;
    k_step2<<<256, 512, 0, stream>>>(Xbuf, hin, hout, cst, wcat, bias, lengths, t);
  }
  // final h in hbuf0 (t=63 writes hbuf0)

  k_scores<<<1024, 256, 0, stream>>>(uv, cc, cid, sbuf);
  k_role<<<64, 256, 0, stream>>>(sbuf, cid, hbuf0, rs);
  k_mha<<<8, 256, 0, stream>>>(rs, Wq, bq, Wk, bk, Wv, bv, attout);
  k_out<<<1, 256, 0, stream>>>(attout, Wo, bo, out);
}